// Round 1
// baseline (1023.914 us; speedup 1.0000x reference)
//
#include <hip/hip_runtime.h>

#define NT 8192      // tokens
#define HD 2048      // hidden
#define NE 8         // experts
#define ID 1408      // inter
#define LOGIT_OFF 16777216

typedef __bf16 bf16x8 __attribute__((ext_vector_type(8)));
typedef float f32x4 __attribute__((ext_vector_type(4)));

__device__ inline bf16x8 cvt_bf8(float4 a, float4 b) {
    bf16x8 v;
    v[0] = (__bf16)a.x; v[1] = (__bf16)a.y; v[2] = (__bf16)a.z; v[3] = (__bf16)a.w;
    v[4] = (__bf16)b.x; v[5] = (__bf16)b.y; v[6] = (__bf16)b.z; v[7] = (__bf16)b.w;
    return v;
}

// ---------------- router: logits (fp32 exact), top2, coef, expert lists ----
__global__ __launch_bounds__(256) void router_kernel(
    const float* __restrict__ x, const float* __restrict__ gw,
    float* __restrict__ logits, int* __restrict__ cnt,
    int* __restrict__ list, float* __restrict__ coef)
{
    const int wv = threadIdx.x >> 6, lane = threadIdx.x & 63;
    const int t = blockIdx.x * 4 + wv;
    const float* xt = x + (size_t)t * HD;
    float acc[NE];
#pragma unroll
    for (int e = 0; e < NE; ++e) acc[e] = 0.f;
    for (int k = lane; k < HD; k += 64) {
        float xv = xt[k];
#pragma unroll
        for (int e = 0; e < NE; ++e) acc[e] = fmaf(xv, gw[e * HD + k], acc[e]);
    }
#pragma unroll
    for (int off = 32; off > 0; off >>= 1) {
#pragma unroll
        for (int e = 0; e < NE; ++e) acc[e] += __shfl_down(acc[e], off);
    }
    if (lane == 0) {
#pragma unroll
        for (int e = 0; e < NE; ++e) logits[(size_t)t * NE + e] = acc[e];
        int b = 0;
#pragma unroll
        for (int e = 1; e < NE; ++e) if (acc[e] > acc[b]) b = e;
        int s = (b == 0) ? 1 : 0;
#pragma unroll
        for (int e = 0; e < NE; ++e) if (e != b && acc[e] > acc[s]) s = e;
        float er = __expf(acc[s] - acc[b]);
        float p1 = 1.f / (1.f + er);
        float p2 = er / (1.f + er);
#pragma unroll
        for (int e = 0; e < NE; ++e) coef[t * NE + e] = 0.f;
        coef[t * NE + b] = p1;
        coef[t * NE + s] = p2;
        int pos = atomicAdd(&cnt[b], 1); list[b * NT + pos] = t;
        pos = atomicAdd(&cnt[s], 1);     list[s * NT + pos] = t;
    }
}

__global__ void prefix_kernel(const int* __restrict__ cnt, int* __restrict__ prefix)
{
    if (threadIdx.x == 0) {
        int s = 0;
        for (int e = 0; e < NE; ++e) { prefix[e] = s; s += cnt[e]; }
    }
}

// ---------------- phase 1: h = silu(x@w1^T) * (x@w3^T), gathered rows ------
// tile: BM=128, BN=64 (h cols), BK=32. 4 waves (2x2), wave tile 64x32, dual acc.
__global__ __launch_bounds__(256) void phase1_kernel(
    const float* __restrict__ x, const float* __restrict__ w13,
    const int* __restrict__ cnt, const int* __restrict__ prefix,
    const int* __restrict__ list, __bf16* __restrict__ h)
{
    const int e = blockIdx.z;
    const int cnt_e = cnt[e];
    const int mtile = blockIdx.y;
    if (mtile * 128 >= cnt_e) return;
    const int ntile = blockIdx.x;
    const int base = prefix[e];
    const int rem = cnt_e - mtile * 128;

    __shared__ __align__(16) __bf16 sA[128][40];
    __shared__ __align__(16) __bf16 sB1[64][40];
    __shared__ __align__(16) __bf16 sB2[64][40];

    const int tid = threadIdx.x;
    const int lane = tid & 63;
    const int wv = tid >> 6;
    const int wr = wv >> 1;   // 0..1 (rows)
    const int wc = wv & 1;    // 0..1 (cols)

    // A staging: row = tid>>1 (0..127), half = tid&1 -> 16 floats
    const int ar = tid >> 1, ah = tid & 1;
    const int arc = (ar < rem) ? ar : (rem - 1);
    const int tok = list[e * NT + mtile * 128 + arc];
    const float* xa = x + (size_t)tok * HD + ah * 16;

    // B staging: row = tid>>2 (0..63), q = tid&3 -> 8 floats each (B1 and B2)
    const int br = tid >> 2, bq = tid & 3;
    const float* w13e = w13 + (size_t)e * (2 * ID) * HD;
    const float* b1p = w13e + (size_t)(ntile * 64 + br) * HD + bq * 8;
    const float* b2p = w13e + (size_t)(ID + ntile * 64 + br) * HD + bq * 8;

    f32x4 acc1[4][2], acc2[4][2];
#pragma unroll
    for (int m = 0; m < 4; ++m)
#pragma unroll
        for (int n = 0; n < 2; ++n) {
            acc1[m][n] = (f32x4){0.f, 0.f, 0.f, 0.f};
            acc2[m][n] = (f32x4){0.f, 0.f, 0.f, 0.f};
        }

    const int kb = (lane >> 4) * 8;
    const int fr = lane & 15;
    const int fq = lane >> 4;

    for (int k0 = 0; k0 < HD; k0 += 32) {
        __syncthreads();
        {
            const float4* p = (const float4*)(xa + k0);
            float4 f0 = p[0], f1 = p[1], f2 = p[2], f3 = p[3];
            *(bf16x8*)&sA[ar][ah * 16] = cvt_bf8(f0, f1);
            *(bf16x8*)&sA[ar][ah * 16 + 8] = cvt_bf8(f2, f3);
        }
        {
            const float4* p = (const float4*)(b1p + k0);
            float4 f0 = p[0], f1 = p[1];
            *(bf16x8*)&sB1[br][bq * 8] = cvt_bf8(f0, f1);
        }
        {
            const float4* p = (const float4*)(b2p + k0);
            float4 f0 = p[0], f1 = p[1];
            *(bf16x8*)&sB2[br][bq * 8] = cvt_bf8(f0, f1);
        }
        __syncthreads();

        bf16x8 af[4], b1f[2], b2f[2];
#pragma unroll
        for (int m = 0; m < 4; ++m)
            af[m] = *(const bf16x8*)&sA[wr * 64 + m * 16 + fr][kb];
#pragma unroll
        for (int n = 0; n < 2; ++n) {
            b1f[n] = *(const bf16x8*)&sB1[wc * 32 + n * 16 + fr][kb];
            b2f[n] = *(const bf16x8*)&sB2[wc * 32 + n * 16 + fr][kb];
        }
#pragma unroll
        for (int m = 0; m < 4; ++m)
#pragma unroll
            for (int n = 0; n < 2; ++n) {
                acc1[m][n] = __builtin_amdgcn_mfma_f32_16x16x32_bf16(af[m], b1f[n], acc1[m][n], 0, 0, 0);
                acc2[m][n] = __builtin_amdgcn_mfma_f32_16x16x32_bf16(af[m], b2f[n], acc2[m][n], 0, 0, 0);
            }
    }

    // epilogue: h = silu(g1) * g2
#pragma unroll
    for (int m = 0; m < 4; ++m) {
#pragma unroll
        for (int j = 0; j < 4; ++j) {
            const int rl = wr * 64 + m * 16 + fq * 4 + j;
            if (rl < rem) {
                const size_t hrow = (size_t)(base + mtile * 128 + rl) * ID;
#pragma unroll
                for (int n = 0; n < 2; ++n) {
                    float g1 = acc1[m][n][j];
                    float g2 = acc2[m][n][j];
                    float hv = g1 / (1.f + __expf(-g1)) * g2;
                    h[hrow + ntile * 64 + wc * 32 + n * 16 + fr] = (__bf16)hv;
                }
            }
        }
    }
}

// ---------------- phase 2: out += ce * (h @ w2^T) --------------------------
// tile: BM=128, BN=128, BK=32. 4 waves (2x2), wave tile 64x64.
__global__ __launch_bounds__(256) void phase2_kernel(
    const __bf16* __restrict__ h, const float* __restrict__ w2,
    const int* __restrict__ cnt, const int* __restrict__ prefix,
    const int* __restrict__ list, const float* __restrict__ coef,
    float* __restrict__ out)
{
    const int e = blockIdx.z;
    const int cnt_e = cnt[e];
    const int mtile = blockIdx.y;
    if (mtile * 128 >= cnt_e) return;
    const int ntile = blockIdx.x;
    const int base = prefix[e];
    const int rem = cnt_e - mtile * 128;

    __shared__ __align__(16) __bf16 sA[128][40];
    __shared__ __align__(16) __bf16 sB[128][40];

    const int tid = threadIdx.x;
    const int lane = tid & 63;
    const int wv = tid >> 6;
    const int wr = wv >> 1;
    const int wc = wv & 1;

    const int ar = tid >> 1, ah = tid & 1;
    const int arc = (ar < rem) ? ar : (rem - 1);
    const __bf16* hap = h + (size_t)(base + mtile * 128 + arc) * ID + ah * 16;

    const float* w2e = w2 + (size_t)e * HD * ID;
    const float* bp = w2e + (size_t)(ntile * 128 + ar) * ID + ah * 16;

    f32x4 acc[4][4];
#pragma unroll
    for (int m = 0; m < 4; ++m)
#pragma unroll
        for (int n = 0; n < 4; ++n) acc[m][n] = (f32x4){0.f, 0.f, 0.f, 0.f};

    const int kb = (lane >> 4) * 8;
    const int fr = lane & 15;
    const int fq = lane >> 4;

    for (int k0 = 0; k0 < ID; k0 += 32) {
        __syncthreads();
        {
            const bf16x8* pa = (const bf16x8*)(hap + k0);
            *(bf16x8*)&sA[ar][ah * 16] = pa[0];
            *(bf16x8*)&sA[ar][ah * 16 + 8] = pa[1];
        }
        {
            const float4* p = (const float4*)(bp + k0);
            float4 f0 = p[0], f1 = p[1], f2 = p[2], f3 = p[3];
            *(bf16x8*)&sB[ar][ah * 16] = cvt_bf8(f0, f1);
            *(bf16x8*)&sB[ar][ah * 16 + 8] = cvt_bf8(f2, f3);
        }
        __syncthreads();

        bf16x8 af[4], bf[4];
#pragma unroll
        for (int m = 0; m < 4; ++m)
            af[m] = *(const bf16x8*)&sA[wr * 64 + m * 16 + fr][kb];
#pragma unroll
        for (int n = 0; n < 4; ++n)
            bf[n] = *(const bf16x8*)&sB[wc * 64 + n * 16 + fr][kb];
#pragma unroll
        for (int m = 0; m < 4; ++m)
#pragma unroll
            for (int n = 0; n < 4; ++n)
                acc[m][n] = __builtin_amdgcn_mfma_f32_16x16x32_bf16(af[m], bf[n], acc[m][n], 0, 0, 0);
    }

#pragma unroll
    for (int m = 0; m < 4; ++m) {
#pragma unroll
        for (int j = 0; j < 4; ++j) {
            const int rl = wr * 64 + m * 16 + fq * 4 + j;
            if (rl < rem) {
                const int t = list[e * NT + mtile * 128 + rl];
                const float ce = coef[t * NE + e];
                float* orow = out + (size_t)t * HD;
#pragma unroll
                for (int n = 0; n < 4; ++n) {
                    const int col = ntile * 128 + wc * 64 + n * 16 + fr;
                    atomicAdd(&orow[col], ce * acc[m][n][j]);
                }
            }
        }
    }
}

extern "C" void kernel_launch(void* const* d_in, const int* in_sizes, int n_in,
                              void* d_out, int out_size, void* d_ws, size_t ws_size,
                              hipStream_t stream)
{
    const float* x   = (const float*)d_in[0];   // 8192 x 2048
    const float* gw  = (const float*)d_in[1];   // 8 x 2048
    const float* w13 = (const float*)d_in[2];   // 8 x 2816 x 2048
    const float* w2  = (const float*)d_in[3];   // 8 x 2048 x 1408
    float* out = (float*)d_out;                 // 16777216 out + 65536 logits

    char* ws = (char*)d_ws;
    int* cnt = (int*)ws;                        // 8 ints
    int* prefix = (int*)(ws + 32);              // 8 ints
    int* list = (int*)(ws + 64);                // 8 x 8192 ints = 256 KB
    float* coef = (float*)(ws + 64 + NE * NT * 4);          // 8192 x 8 f32 = 256 KB
    __bf16* h = (__bf16*)(ws + 64 + NE * NT * 4 + NT * NE * 4 + 64); // 16384 x 1408 bf16

    hipMemsetAsync(cnt, 0, 32, stream);
    hipMemsetAsync(d_out, 0, (size_t)LOGIT_OFF * 4, stream);

    router_kernel<<<NT / 4, 256, 0, stream>>>(x, gw, out + LOGIT_OFF, cnt, list, coef);
    prefix_kernel<<<1, 64, 0, stream>>>(cnt, prefix);
    phase1_kernel<<<dim3(ID / 64, NT / 128, NE), 256, 0, stream>>>(x, w13, cnt, prefix, list, h);
    phase2_kernel<<<dim3(HD / 128, NT / 128, NE), 256, 0, stream>>>(h, w2, cnt, prefix, list, coef, out);
}

// Round 2
// 830.768 us; speedup vs baseline: 1.2325x; 1.2325x over previous
//
#include <hip/hip_runtime.h>
#include <stdint.h>

#define NT 8192      // tokens
#define HD 2048      // hidden
#define NE 8         // experts
#define ID 1408      // inter
#define LOGIT_OFF 16777216

typedef __bf16 bf16x8 __attribute__((ext_vector_type(8)));
typedef float f32x4 __attribute__((ext_vector_type(4)));

__device__ inline bf16x8 cvt_bf8(float4 a, float4 b) {
    bf16x8 v;
    v[0] = (__bf16)a.x; v[1] = (__bf16)a.y; v[2] = (__bf16)a.z; v[3] = (__bf16)a.w;
    v[4] = (__bf16)b.x; v[5] = (__bf16)b.y; v[6] = (__bf16)b.z; v[7] = (__bf16)b.w;
    return v;
}

__device__ inline void gload16(const void* g, void* l) {
    __builtin_amdgcn_global_load_lds(
        (const __attribute__((address_space(1))) unsigned int*)g,
        (__attribute__((address_space(3))) unsigned int*)l, 16, 0, 0);
}

// ---------------- fp32 -> bf16 convert (grid-stride, 8 elem/thread/step) ---
__global__ __launch_bounds__(256) void cvt_kernel(
    const float* __restrict__ src, __bf16* __restrict__ dst, int n8)
{
    for (int i = blockIdx.x * blockDim.x + threadIdx.x; i < n8;
         i += gridDim.x * blockDim.x) {
        const float4* p = (const float4*)(src + (size_t)i * 8);
        float4 a = p[0], b = p[1];
        *(bf16x8*)(dst + (size_t)i * 8) = cvt_bf8(a, b);
    }
}

// ---------------- router: logits (fp32 exact), top2, coef, expert lists ----
__global__ __launch_bounds__(256) void router_kernel(
    const float* __restrict__ x, const float* __restrict__ gw,
    float* __restrict__ logits, int* __restrict__ cnt,
    int* __restrict__ list, float* __restrict__ coef)
{
    const int wv = threadIdx.x >> 6, lane = threadIdx.x & 63;
    const int t = blockIdx.x * 4 + wv;
    const float* xt = x + (size_t)t * HD;
    float acc[NE];
#pragma unroll
    for (int e = 0; e < NE; ++e) acc[e] = 0.f;
    for (int k = lane; k < HD; k += 64) {
        float xv = xt[k];
#pragma unroll
        for (int e = 0; e < NE; ++e) acc[e] = fmaf(xv, gw[e * HD + k], acc[e]);
    }
#pragma unroll
    for (int off = 32; off > 0; off >>= 1) {
#pragma unroll
        for (int e = 0; e < NE; ++e) acc[e] += __shfl_down(acc[e], off);
    }
    if (lane == 0) {
#pragma unroll
        for (int e = 0; e < NE; ++e) logits[(size_t)t * NE + e] = acc[e];
        int b = 0;
#pragma unroll
        for (int e = 1; e < NE; ++e) if (acc[e] > acc[b]) b = e;
        int s = (b == 0) ? 1 : 0;
#pragma unroll
        for (int e = 0; e < NE; ++e) if (e != b && acc[e] > acc[s]) s = e;
        float er = __expf(acc[s] - acc[b]);
        float p1 = 1.f / (1.f + er);
        float p2 = er / (1.f + er);
#pragma unroll
        for (int e = 0; e < NE; ++e) coef[t * NE + e] = 0.f;
        coef[t * NE + b] = p1;
        coef[t * NE + s] = p2;
        int pos = atomicAdd(&cnt[b], 1); list[b * NT + pos] = t;
        pos = atomicAdd(&cnt[s], 1);     list[s * NT + pos] = t;
    }
}

__global__ void prefix_kernel(const int* __restrict__ cnt, int* __restrict__ prefix)
{
    if (threadIdx.x == 0) {
        int s = 0;
        for (int e = 0; e < NE; ++e) { prefix[e] = s; s += cnt[e]; }
    }
}

// ============ bf16 fast path ===============================================
// phase 1: h = silu(x@w1^T) * (x@w3^T). BM=128, BN=64 hcols, BK=64.
// 4 waves (2x2). global_load_lds staging, XOR-swizzled source (m173 pattern).
__global__ __launch_bounds__(256) void phase1_bf16(
    const __bf16* __restrict__ xb, const __bf16* __restrict__ w13b,
    const int* __restrict__ cnt, const int* __restrict__ prefix,
    const int* __restrict__ list, __bf16* __restrict__ h)
{
    const int e = blockIdx.z;
    const int cnt_e = cnt[e];
    const int mtile = blockIdx.y;
    if (mtile * 128 >= cnt_e) return;
    const int ntile = blockIdx.x;
    const int base = prefix[e];
    const int rem = cnt_e - mtile * 128;

    __shared__ __align__(16) __bf16 sA[128][64];   // 16 KB
    __shared__ __align__(16) __bf16 sB1[64][64];   // 8 KB
    __shared__ __align__(16) __bf16 sB3[64][64];   // 8 KB

    const int tid = threadIdx.x;
    const int lane = tid & 63;
    const int wv = tid >> 6;
    const int wr = wv >> 1;
    const int wc = wv & 1;

    // staging geometry: per issue a wave covers 8 rows x 8 chunks(16B).
    const int ri = lane >> 3;        // row within issue (0..7)
    const int ch = lane & 7;         // LDS chunk (16B units)
    const int sc = ch ^ ri;          // swizzled source chunk
    const int scoff = sc * 8;        // element offset within row

    // A sources: 4 issues -> rows wv*32 + j*8 + ri
    const __bf16* aS[4];
#pragma unroll
    for (int j = 0; j < 4; ++j) {
        int row = wv * 32 + j * 8 + ri;
        int rr = (row < rem) ? row : (rem - 1);
        int tok = list[e * NT + mtile * 128 + rr];
        aS[j] = xb + (size_t)tok * HD + scoff;
    }
    // B sources: 2 issues each for w1 and w3 -> rows wv*16 + j*8 + ri
    const __bf16* b1S[2];
    const __bf16* b3S[2];
    const size_t w13row0 = (size_t)e * (2 * ID) + (size_t)ntile * 64;
#pragma unroll
    for (int j = 0; j < 2; ++j) {
        int row = wv * 16 + j * 8 + ri;
        b1S[j] = w13b + (w13row0 + row) * HD + scoff;
        b3S[j] = w13b + (w13row0 + ID + row) * HD + scoff;
    }

    f32x4 acc1[4][2], acc3[4][2];
#pragma unroll
    for (int m = 0; m < 4; ++m)
#pragma unroll
        for (int n = 0; n < 2; ++n) {
            acc1[m][n] = (f32x4){0.f, 0.f, 0.f, 0.f};
            acc3[m][n] = (f32x4){0.f, 0.f, 0.f, 0.f};
        }

    const int fr = lane & 15;
    const int fq = lane >> 4;

    for (int k0 = 0; k0 < HD; k0 += 64) {
        __syncthreads();
#pragma unroll
        for (int j = 0; j < 4; ++j)
            gload16(aS[j] + k0, &sA[wv * 32 + j * 8][0]);
#pragma unroll
        for (int j = 0; j < 2; ++j) {
            gload16(b1S[j] + k0, &sB1[wv * 16 + j * 8][0]);
            gload16(b3S[j] + k0, &sB3[wv * 16 + j * 8][0]);
        }
        __syncthreads();   // compiler drains vmcnt(0) here -> tiles ready

#pragma unroll
        for (int ks = 0; ks < 2; ++ks) {
            const int cc = ((ks << 2) | fq) ^ (fr & 7);   // swizzled chunk
            bf16x8 af[4], b1f[2], b3f[2];
#pragma unroll
            for (int m = 0; m < 4; ++m)
                af[m] = *(const bf16x8*)&sA[wr * 64 + m * 16 + fr][cc * 8];
#pragma unroll
            for (int n = 0; n < 2; ++n) {
                b1f[n] = *(const bf16x8*)&sB1[wc * 32 + n * 16 + fr][cc * 8];
                b3f[n] = *(const bf16x8*)&sB3[wc * 32 + n * 16 + fr][cc * 8];
            }
#pragma unroll
            for (int m = 0; m < 4; ++m)
#pragma unroll
                for (int n = 0; n < 2; ++n) {
                    acc1[m][n] = __builtin_amdgcn_mfma_f32_16x16x32_bf16(af[m], b1f[n], acc1[m][n], 0, 0, 0);
                    acc3[m][n] = __builtin_amdgcn_mfma_f32_16x16x32_bf16(af[m], b3f[n], acc3[m][n], 0, 0, 0);
                }
        }
    }

    // epilogue: h = silu(g1) * g3
#pragma unroll
    for (int m = 0; m < 4; ++m) {
#pragma unroll
        for (int j = 0; j < 4; ++j) {
            const int rl = wr * 64 + m * 16 + fq * 4 + j;
            if (rl < rem) {
                const size_t hrow = (size_t)(base + mtile * 128 + rl) * ID;
#pragma unroll
                for (int n = 0; n < 2; ++n) {
                    float g1 = acc1[m][n][j];
                    float g3 = acc3[m][n][j];
                    float hv = g1 / (1.f + __expf(-g1)) * g3;
                    h[hrow + ntile * 64 + wc * 32 + n * 16 + fr] = (__bf16)hv;
                }
            }
        }
    }
}

// phase 2: out += ce * (h @ w2^T). BM=128, BN=128, BK=64. 4 waves (2x2).
__global__ __launch_bounds__(256) void phase2_bf16(
    const __bf16* __restrict__ h, const __bf16* __restrict__ w2b,
    const int* __restrict__ cnt, const int* __restrict__ prefix,
    const int* __restrict__ list, const float* __restrict__ coef,
    float* __restrict__ out)
{
    const int e = blockIdx.z;
    const int cnt_e = cnt[e];
    const int mtile = blockIdx.y;
    if (mtile * 128 >= cnt_e) return;
    const int ntile = blockIdx.x;
    const int base = prefix[e];
    const int rem = cnt_e - mtile * 128;

    __shared__ __align__(16) __bf16 sA[128][64];   // 16 KB
    __shared__ __align__(16) __bf16 sB[128][64];   // 16 KB

    const int tid = threadIdx.x;
    const int lane = tid & 63;
    const int wv = tid >> 6;
    const int wr = wv >> 1;
    const int wc = wv & 1;

    const int ri = lane >> 3;
    const int ch = lane & 7;
    const int sc = ch ^ ri;
    const int scoff = sc * 8;

    // A sources (h rows are contiguous in list order -> no gather)
    const __bf16* aS[4];
#pragma unroll
    for (int j = 0; j < 4; ++j) {
        int row = wv * 32 + j * 8 + ri;
        int rr = (row < rem) ? row : (rem - 1);
        aS[j] = h + (size_t)(base + mtile * 128 + rr) * ID + scoff;
    }
    // B sources: w2 rows (out cols)
    const __bf16* bS[4];
    const size_t w2row0 = (size_t)e * HD + (size_t)ntile * 128;
#pragma unroll
    for (int j = 0; j < 4; ++j) {
        int row = wv * 32 + j * 8 + ri;
        bS[j] = w2b + (w2row0 + row) * ID + scoff;
    }

    f32x4 acc[4][4];
#pragma unroll
    for (int m = 0; m < 4; ++m)
#pragma unroll
        for (int n = 0; n < 4; ++n) acc[m][n] = (f32x4){0.f, 0.f, 0.f, 0.f};

    const int fr = lane & 15;
    const int fq = lane >> 4;

    for (int k0 = 0; k0 < ID; k0 += 64) {
        __syncthreads();
#pragma unroll
        for (int j = 0; j < 4; ++j) {
            gload16(aS[j] + k0, &sA[wv * 32 + j * 8][0]);
            gload16(bS[j] + k0, &sB[wv * 32 + j * 8][0]);
        }
        __syncthreads();

#pragma unroll
        for (int ks = 0; ks < 2; ++ks) {
            const int cc = ((ks << 2) | fq) ^ (fr & 7);
            bf16x8 af[4], bf[4];
#pragma unroll
            for (int m = 0; m < 4; ++m)
                af[m] = *(const bf16x8*)&sA[wr * 64 + m * 16 + fr][cc * 8];
#pragma unroll
            for (int n = 0; n < 4; ++n)
                bf[n] = *(const bf16x8*)&sB[wc * 64 + n * 16 + fr][cc * 8];
#pragma unroll
            for (int m = 0; m < 4; ++m)
#pragma unroll
                for (int n = 0; n < 4; ++n)
                    acc[m][n] = __builtin_amdgcn_mfma_f32_16x16x32_bf16(af[m], bf[n], acc[m][n], 0, 0, 0);
        }
    }

#pragma unroll
    for (int m = 0; m < 4; ++m) {
#pragma unroll
        for (int j = 0; j < 4; ++j) {
            const int rl = wr * 64 + m * 16 + fq * 4 + j;
            if (rl < rem) {
                const int t = list[e * NT + mtile * 128 + rl];
                const float ce = coef[t * NE + e];
                float* orow = out + (size_t)t * HD;
#pragma unroll
                for (int n = 0; n < 4; ++n) {
                    const int col = ntile * 128 + wc * 64 + n * 16 + fr;
                    atomicAdd(&orow[col], ce * acc[m][n][j]);
                }
            }
        }
    }
}

// ============ fp32 fallback path (round-1, known-good) =====================
__global__ __launch_bounds__(256) void phase1_f32(
    const float* __restrict__ x, const float* __restrict__ w13,
    const int* __restrict__ cnt, const int* __restrict__ prefix,
    const int* __restrict__ list, __bf16* __restrict__ h)
{
    const int e = blockIdx.z;
    const int cnt_e = cnt[e];
    const int mtile = blockIdx.y;
    if (mtile * 128 >= cnt_e) return;
    const int ntile = blockIdx.x;
    const int base = prefix[e];
    const int rem = cnt_e - mtile * 128;

    __shared__ __align__(16) __bf16 sA[128][40];
    __shared__ __align__(16) __bf16 sB1[64][40];
    __shared__ __align__(16) __bf16 sB2[64][40];

    const int tid = threadIdx.x;
    const int lane = tid & 63;
    const int wv = tid >> 6;
    const int wr = wv >> 1;
    const int wc = wv & 1;

    const int ar = tid >> 1, ah = tid & 1;
    const int arc = (ar < rem) ? ar : (rem - 1);
    const int tok = list[e * NT + mtile * 128 + arc];
    const float* xa = x + (size_t)tok * HD + ah * 16;

    const int br = tid >> 2, bq = tid & 3;
    const float* w13e = w13 + (size_t)e * (2 * ID) * HD;
    const float* b1p = w13e + (size_t)(ntile * 64 + br) * HD + bq * 8;
    const float* b2p = w13e + (size_t)(ID + ntile * 64 + br) * HD + bq * 8;

    f32x4 acc1[4][2], acc2[4][2];
#pragma unroll
    for (int m = 0; m < 4; ++m)
#pragma unroll
        for (int n = 0; n < 2; ++n) {
            acc1[m][n] = (f32x4){0.f, 0.f, 0.f, 0.f};
            acc2[m][n] = (f32x4){0.f, 0.f, 0.f, 0.f};
        }

    const int kb = (lane >> 4) * 8;
    const int fr = lane & 15;
    const int fq = lane >> 4;

    for (int k0 = 0; k0 < HD; k0 += 32) {
        __syncthreads();
        {
            const float4* p = (const float4*)(xa + k0);
            float4 f0 = p[0], f1 = p[1], f2 = p[2], f3 = p[3];
            *(bf16x8*)&sA[ar][ah * 16] = cvt_bf8(f0, f1);
            *(bf16x8*)&sA[ar][ah * 16 + 8] = cvt_bf8(f2, f3);
        }
        {
            const float4* p = (const float4*)(b1p + k0);
            float4 f0 = p[0], f1 = p[1];
            *(bf16x8*)&sB1[br][bq * 8] = cvt_bf8(f0, f1);
        }
        {
            const float4* p = (const float4*)(b2p + k0);
            float4 f0 = p[0], f1 = p[1];
            *(bf16x8*)&sB2[br][bq * 8] = cvt_bf8(f0, f1);
        }
        __syncthreads();

        bf16x8 af[4], b1f[2], b2f[2];
#pragma unroll
        for (int m = 0; m < 4; ++m)
            af[m] = *(const bf16x8*)&sA[wr * 64 + m * 16 + fr][kb];
#pragma unroll
        for (int n = 0; n < 2; ++n) {
            b1f[n] = *(const bf16x8*)&sB1[wc * 32 + n * 16 + fr][kb];
            b2f[n] = *(const bf16x8*)&sB2[wc * 32 + n * 16 + fr][kb];
        }
#pragma unroll
        for (int m = 0; m < 4; ++m)
#pragma unroll
            for (int n = 0; n < 2; ++n) {
                acc1[m][n] = __builtin_amdgcn_mfma_f32_16x16x32_bf16(af[m], b1f[n], acc1[m][n], 0, 0, 0);
                acc2[m][n] = __builtin_amdgcn_mfma_f32_16x16x32_bf16(af[m], b2f[n], acc2[m][n], 0, 0, 0);
            }
    }

#pragma unroll
    for (int m = 0; m < 4; ++m) {
#pragma unroll
        for (int j = 0; j < 4; ++j) {
            const int rl = wr * 64 + m * 16 + fq * 4 + j;
            if (rl < rem) {
                const size_t hrow = (size_t)(base + mtile * 128 + rl) * ID;
#pragma unroll
                for (int n = 0; n < 2; ++n) {
                    float g1 = acc1[m][n][j];
                    float g2 = acc2[m][n][j];
                    float hv = g1 / (1.f + __expf(-g1)) * g2;
                    h[hrow + ntile * 64 + wc * 32 + n * 16 + fr] = (__bf16)hv;
                }
            }
        }
    }
}

__global__ __launch_bounds__(256) void phase2_f32(
    const __bf16* __restrict__ h, const float* __restrict__ w2,
    const int* __restrict__ cnt, const int* __restrict__ prefix,
    const int* __restrict__ list, const float* __restrict__ coef,
    float* __restrict__ out)
{
    const int e = blockIdx.z;
    const int cnt_e = cnt[e];
    const int mtile = blockIdx.y;
    if (mtile * 128 >= cnt_e) return;
    const int ntile = blockIdx.x;
    const int base = prefix[e];
    const int rem = cnt_e - mtile * 128;

    __shared__ __align__(16) __bf16 sA[128][40];
    __shared__ __align__(16) __bf16 sB[128][40];

    const int tid = threadIdx.x;
    const int lane = tid & 63;
    const int wv = tid >> 6;
    const int wr = wv >> 1;
    const int wc = wv & 1;

    const int ar = tid >> 1, ah = tid & 1;
    const int arc = (ar < rem) ? ar : (rem - 1);
    const __bf16* hap = h + (size_t)(base + mtile * 128 + arc) * ID + ah * 16;

    const float* w2e = w2 + (size_t)e * HD * ID;
    const float* bp = w2e + (size_t)(ntile * 128 + ar) * ID + ah * 16;

    f32x4 acc[4][4];
#pragma unroll
    for (int m = 0; m < 4; ++m)
#pragma unroll
        for (int n = 0; n < 4; ++n) acc[m][n] = (f32x4){0.f, 0.f, 0.f, 0.f};

    const int kb = (lane >> 4) * 8;
    const int fr = lane & 15;
    const int fq = lane >> 4;

    for (int k0 = 0; k0 < ID; k0 += 32) {
        __syncthreads();
        {
            const bf16x8* pa = (const bf16x8*)(hap + k0);
            *(bf16x8*)&sA[ar][ah * 16] = pa[0];
            *(bf16x8*)&sA[ar][ah * 16 + 8] = pa[1];
        }
        {
            const float4* p = (const float4*)(bp + k0);
            float4 f0 = p[0], f1 = p[1], f2 = p[2], f3 = p[3];
            *(bf16x8*)&sB[ar][ah * 16] = cvt_bf8(f0, f1);
            *(bf16x8*)&sB[ar][ah * 16 + 8] = cvt_bf8(f2, f3);
        }
        __syncthreads();

        bf16x8 af[4], bf[4];
#pragma unroll
        for (int m = 0; m < 4; ++m)
            af[m] = *(const bf16x8*)&sA[wr * 64 + m * 16 + fr][kb];
#pragma unroll
        for (int n = 0; n < 4; ++n)
            bf[n] = *(const bf16x8*)&sB[wc * 64 + n * 16 + fr][kb];
#pragma unroll
        for (int m = 0; m < 4; ++m)
#pragma unroll
            for (int n = 0; n < 4; ++n)
                acc[m][n] = __builtin_amdgcn_mfma_f32_16x16x32_bf16(af[m], bf[n], acc[m][n], 0, 0, 0);
    }

#pragma unroll
    for (int m = 0; m < 4; ++m) {
#pragma unroll
        for (int j = 0; j < 4; ++j) {
            const int rl = wr * 64 + m * 16 + fq * 4 + j;
            if (rl < rem) {
                const int t = list[e * NT + mtile * 128 + rl];
                const float ce = coef[t * NE + e];
                float* orow = out + (size_t)t * HD;
#pragma unroll
                for (int n = 0; n < 4; ++n) {
                    const int col = ntile * 128 + wc * 64 + n * 16 + fr;
                    atomicAdd(&orow[col], ce * acc[m][n][j]);
                }
            }
        }
    }
}

extern "C" void kernel_launch(void* const* d_in, const int* in_sizes, int n_in,
                              void* d_out, int out_size, void* d_ws, size_t ws_size,
                              hipStream_t stream)
{
    const float* x   = (const float*)d_in[0];   // 8192 x 2048
    const float* gw  = (const float*)d_in[1];   // 8 x 2048
    const float* w13 = (const float*)d_in[2];   // 8 x 2816 x 2048
    const float* w2  = (const float*)d_in[3];   // 8 x 2048 x 1408
    float* out = (float*)d_out;                 // 16777216 out + 65536 logits

    char* ws = (char*)d_ws;
    int* cnt = (int*)ws;
    int* prefix = (int*)(ws + 32);
    int* list = (int*)(ws + 64);
    float* coef = (float*)(ws + 64 + NE * NT * 4);
    size_t off = ((size_t)64 + NE * NT * 4 + NT * NE * 4 + 255) & ~(size_t)255;

    const size_t nx = (size_t)NT * HD;            // 16.8M
    const size_t nw13 = (size_t)NE * 2 * ID * HD; // 46.1M
    const size_t nw2 = (size_t)NE * HD * ID;      // 23.1M
    const size_t nh = (size_t)2 * NT * ID;        // 23.1M elems (16384x1408)

    const size_t need = off + (nx + nw13 + nw2 + nh) * 2;

    hipMemsetAsync(cnt, 0, 32, stream);
    hipMemsetAsync(d_out, 0, (size_t)LOGIT_OFF * 4, stream);

    if (ws_size >= need) {
        __bf16* xb   = (__bf16*)(ws + off);
        __bf16* w13b = xb + nx;
        __bf16* w2b  = w13b + nw13;
        __bf16* h    = w2b + nw2;

        cvt_kernel<<<2048, 256, 0, stream>>>(x, xb, (int)(nx / 8));
        cvt_kernel<<<2048, 256, 0, stream>>>(w13, w13b, (int)(nw13 / 8));
        cvt_kernel<<<2048, 256, 0, stream>>>(w2, w2b, (int)(nw2 / 8));
        router_kernel<<<NT / 4, 256, 0, stream>>>(x, gw, out + LOGIT_OFF, cnt, list, coef);
        prefix_kernel<<<1, 64, 0, stream>>>(cnt, prefix);
        phase1_bf16<<<dim3(ID / 64, NT / 128, NE), 256, 0, stream>>>(xb, w13b, cnt, prefix, list, h);
        phase2_bf16<<<dim3(HD / 128, NT / 128, NE), 256, 0, stream>>>(h, w2b, cnt, prefix, list, coef, out);
    } else {
        __bf16* h = (__bf16*)(ws + off);
        router_kernel<<<NT / 4, 256, 0, stream>>>(x, gw, out + LOGIT_OFF, cnt, list, coef);
        prefix_kernel<<<1, 64, 0, stream>>>(cnt, prefix);
        phase1_f32<<<dim3(ID / 64, NT / 128, NE), 256, 0, stream>>>(x, w13, cnt, prefix, list, h);
        phase2_f32<<<dim3(HD / 128, NT / 128, NE), 256, 0, stream>>>(h, w2, cnt, prefix, list, coef, out);
    }
}

// Round 3
// 727.794 us; speedup vs baseline: 1.4069x; 1.1415x over previous
//
#include <hip/hip_runtime.h>
#include <stdint.h>

#define NT 8192      // tokens
#define HD 2048      // hidden
#define NE 8         // experts
#define ID 1408      // inter
#define LOGIT_OFF 16777216

typedef __bf16 bf16x8 __attribute__((ext_vector_type(8)));
typedef float f32x4 __attribute__((ext_vector_type(4)));

__device__ inline bf16x8 cvt_bf8(float4 a, float4 b) {
    bf16x8 v;
    v[0] = (__bf16)a.x; v[1] = (__bf16)a.y; v[2] = (__bf16)a.z; v[3] = (__bf16)a.w;
    v[4] = (__bf16)b.x; v[5] = (__bf16)b.y; v[6] = (__bf16)b.z; v[7] = (__bf16)b.w;
    return v;
}

__device__ inline void gload16(const void* g, void* l) {
    __builtin_amdgcn_global_load_lds(
        (const __attribute__((address_space(1))) unsigned int*)g,
        (__attribute__((address_space(3))) unsigned int*)l, 16, 0, 0);
}

#define WAITV4  asm volatile("s_waitcnt vmcnt(4)" ::: "memory")
#define BARRIER do { __builtin_amdgcn_s_barrier(); asm volatile("" ::: "memory"); } while (0)

// ---------------- fp32 -> bf16 convert (weights) ---------------------------
__global__ __launch_bounds__(256) void cvt_kernel(
    const float* __restrict__ src, __bf16* __restrict__ dst, int n8)
{
    for (int i = blockIdx.x * blockDim.x + threadIdx.x; i < n8;
         i += gridDim.x * blockDim.x) {
        const float4* p = (const float4*)(src + (size_t)i * 8);
        float4 a = p[0], b = p[1];
        *(bf16x8*)(dst + (size_t)i * 8) = cvt_bf8(a, b);
    }
}

// ---------------- router: logits (fp32 exact), top2, lists; fused x->bf16 --
__global__ __launch_bounds__(256) void router_kernel(
    const float* __restrict__ x, const float* __restrict__ gw,
    float* __restrict__ logits, int* __restrict__ cnt,
    int* __restrict__ list, float* __restrict__ coef, __bf16* __restrict__ xb)
{
    const int wv = threadIdx.x >> 6, lane = threadIdx.x & 63;
    const int t = blockIdx.x * 4 + wv;
    const float* xt = x + (size_t)t * HD;
    float acc[NE];
#pragma unroll
    for (int e = 0; e < NE; ++e) acc[e] = 0.f;
    for (int k = lane; k < HD; k += 64) {
        float xv = xt[k];
#pragma unroll
        for (int e = 0; e < NE; ++e) acc[e] = fmaf(xv, gw[e * HD + k], acc[e]);
    }
#pragma unroll
    for (int off = 32; off > 0; off >>= 1) {
#pragma unroll
        for (int e = 0; e < NE; ++e) acc[e] += __shfl_down(acc[e], off);
    }
    if (lane == 0) {
#pragma unroll
        for (int e = 0; e < NE; ++e) logits[(size_t)t * NE + e] = acc[e];
        int b = 0;
#pragma unroll
        for (int e = 1; e < NE; ++e) if (acc[e] > acc[b]) b = e;
        int s = (b == 0) ? 1 : 0;
#pragma unroll
        for (int e = 0; e < NE; ++e) if (e != b && acc[e] > acc[s]) s = e;
        float er = __expf(acc[s] - acc[b]);
        float p1 = 1.f / (1.f + er);
        float p2 = er / (1.f + er);
#pragma unroll
        for (int e = 0; e < NE; ++e) coef[t * NE + e] = 0.f;
        coef[t * NE + b] = p1;
        coef[t * NE + s] = p2;
        int pos = atomicAdd(&cnt[b], 1); list[b * NT + pos] = t;
        pos = atomicAdd(&cnt[s], 1);     list[s * NT + pos] = t;
    }
    if (xb) {
        for (int c = lane; c < HD / 8; c += 64) {
            const float4* p = (const float4*)(xt + c * 8);
            float4 a = p[0], b2 = p[1];
            *(bf16x8*)(xb + (size_t)t * HD + c * 8) = cvt_bf8(a, b2);
        }
    }
}

__global__ void prefix_kernel(const int* __restrict__ cnt, int* __restrict__ prefix)
{
    if (threadIdx.x == 0) {
        int s = 0;
        for (int e = 0; e < NE; ++e) { prefix[e] = s; s += cnt[e]; }
    }
}

// ============ 256-tile 8-phase bf16 kernels ================================
// Common geometry: BM=256, BK=64, 8 waves (2M x 4N), per-wave out 128 rows.
// LDS: sA[2 parity][2 half][128][64] + sB same = 128 KiB dynamic.
// Phase order per K-tile: (A0,B0) (A0,B1) (A1,B0) (A1,B1); prefetch order for
// tile t+1: A0,B0,B1,A1 (one half = 2 gloads/wave per phase). Derived waits:
// vmcnt(4) at phases 1,2,3 (2 halves in flight behind the needed one).

#define SA(P_,H_) (sA + (((P_)*2 + (H_)) * 128) * 64)
#define SB(P_,H_) (sB + (((P_)*2 + (H_)) * 128) * 64)

#define STAGE_A(P_,H_,J_,K_) gload16(aS[H_][J_] + (K_), SA(P_,H_) + ((J_)*64 + wv*8) * 64)
#define STAGE_B(P_,H_,J_,K_) gload16(bS[H_][J_] + (K_), SB(P_,H_) + ((J_)*64 + wv*8) * 64)

#define READ_A(P_,QM_) do { \
    _Pragma("unroll") for (int m_ = 0; m_ < 4; ++m_) { \
        const __bf16* rp_ = SA(P_,QM_) + (wm*64 + m_*16 + fr) * 64; \
        af[m_][0] = *(const bf16x8*)(rp_ + (((0*4+fq) ^ (fr&7)) * 8)); \
        af[m_][1] = *(const bf16x8*)(rp_ + (((1*4+fq) ^ (fr&7)) * 8)); \
    } } while (0)

#define READ_B(P_,QH_) do { \
    _Pragma("unroll") for (int n_ = 0; n_ < 2; ++n_) { \
        const __bf16* rp_ = SB(P_,QH_) + (wn*32 + n_*16 + fr) * 64; \
        bf[n_][0] = *(const bf16x8*)(rp_ + (((0*4+fq) ^ (fr&7)) * 8)); \
        bf[n_][1] = *(const bf16x8*)(rp_ + (((1*4+fq) ^ (fr&7)) * 8)); \
    } } while (0)

#define MFMA_PHASE(QM_,QH_) do { \
    __builtin_amdgcn_s_setprio(1); \
    _Pragma("unroll") for (int m_ = 0; m_ < 4; ++m_) \
    _Pragma("unroll") for (int n_ = 0; n_ < 2; ++n_) { \
        acc[QM_][QH_][m_][n_] = __builtin_amdgcn_mfma_f32_16x16x32_bf16(af[m_][0], bf[n_][0], acc[QM_][QH_][m_][n_], 0, 0, 0); \
        acc[QM_][QH_][m_][n_] = __builtin_amdgcn_mfma_f32_16x16x32_bf16(af[m_][1], bf[n_][1], acc[QM_][QH_][m_][n_], 0, 0, 0); \
    } \
    __builtin_amdgcn_s_setprio(0); \
} while (0)

// phase 1: h = silu(x@w1^T) * (x@w3^T). Block: 256 rows x 128 h-cols.
// B-half0 = w1 tile, B-half1 = w3 tile; quadrant qh selects the GEMM.
__global__ __launch_bounds__(512, 2) void phase1_bf16(
    const __bf16* __restrict__ xb, const __bf16* __restrict__ w13b,
    const int* __restrict__ cnt, const int* __restrict__ prefix,
    const int* __restrict__ list, __bf16* __restrict__ h)
{
    const int e = blockIdx.z;
    const int cnt_e = cnt[e];
    const int mtile = blockIdx.y;
    if (mtile * 256 >= cnt_e) return;
    const int ntile = blockIdx.x;
    const int base = prefix[e];
    const int rem = cnt_e - mtile * 256;

    extern __shared__ __bf16 smem[];
    __bf16* sA = smem;            // 32768 elems
    __bf16* sB = smem + 32768;

    const int tid = threadIdx.x;
    const int lane = tid & 63;
    const int wv = tid >> 6;      // 0..7
    const int wm = wv >> 2;       // 0..1
    const int wn = wv & 3;        // 0..3
    const int ri = lane >> 3;     // 0..7
    const int ch = lane & 7;
    const int scoff = (ch ^ ri) * 8;
    const int fr = lane & 15;
    const int fq = lane >> 4;     // 0..3

    // A sources: [half qm][issue j]
    const __bf16* aS[2][2];
#pragma unroll
    for (int qm = 0; qm < 2; ++qm)
#pragma unroll
        for (int j = 0; j < 2; ++j) {
            int row = qm * 128 + j * 64 + wv * 8 + ri;
            int rr = (row < rem) ? row : (rem - 1);
            int tok = list[e * NT + mtile * 256 + rr];
            aS[qm][j] = xb + (size_t)tok * HD + scoff;
        }
    // B sources: half0 = w1, half1 = w3
    const __bf16* bS[2][2];
    const size_t w13e = (size_t)e * (2 * ID);
#pragma unroll
    for (int j = 0; j < 2; ++j) {
        int row = ntile * 128 + j * 64 + wv * 8 + ri;
        bS[0][j] = w13b + (w13e + row) * HD + scoff;
        bS[1][j] = w13b + (w13e + ID + row) * HD + scoff;
    }

    f32x4 acc[2][2][4][2];
#pragma unroll
    for (int a0 = 0; a0 < 2; ++a0)
#pragma unroll
        for (int a1 = 0; a1 < 2; ++a1)
#pragma unroll
            for (int m = 0; m < 4; ++m)
#pragma unroll
                for (int n = 0; n < 2; ++n)
                    acc[a0][a1][m][n] = (f32x4){0.f, 0.f, 0.f, 0.f};

    // prologue: tile 0 halves in order A0, B0, B1, A1
    STAGE_A(0,0,0,0); STAGE_A(0,0,1,0);
    STAGE_B(0,0,0,0); STAGE_B(0,0,1,0);
    STAGE_B(0,1,0,0); STAGE_B(0,1,1,0);
    STAGE_A(0,1,0,0); STAGE_A(0,1,1,0);

    const int NTK = HD / 64;   // 32
    bf16x8 af[4][2], bf[2][2];
    for (int t = 0; t < NTK; ++t) {
        const int p = t & 1, q = p ^ 1;
        const int kn = ((t + 1 < NTK) ? (t + 1) : t) * 64;

        // phase 1: (A0, B0)
        WAITV4; BARRIER;
        READ_A(p, 0); READ_B(p, 0);
        STAGE_A(q,0,0,kn); STAGE_A(q,0,1,kn);
        MFMA_PHASE(0, 0);

        // phase 2: (A0, B1)
        WAITV4; BARRIER;
        READ_B(p, 1);
        STAGE_B(q,0,0,kn); STAGE_B(q,0,1,kn);
        MFMA_PHASE(0, 1);

        // phase 3: (A1, B0)
        WAITV4; BARRIER;
        READ_A(p, 1); READ_B(p, 0);
        STAGE_B(q,1,0,kn); STAGE_B(q,1,1,kn);
        MFMA_PHASE(1, 0);

        // phase 4: (A1, B1)
        BARRIER;
        READ_B(p, 1);
        STAGE_A(q,1,0,kn); STAGE_A(q,1,1,kn);
        MFMA_PHASE(1, 1);
    }

    // epilogue: h = silu(g1) * g3
#pragma unroll
    for (int qm = 0; qm < 2; ++qm)
#pragma unroll
        for (int m = 0; m < 4; ++m)
#pragma unroll
            for (int j = 0; j < 4; ++j) {
                const int rl = qm * 128 + wm * 64 + m * 16 + fq * 4 + j;
                if (rl < rem) {
                    const size_t hrow = (size_t)(base + mtile * 256 + rl) * ID;
#pragma unroll
                    for (int n = 0; n < 2; ++n) {
                        float g1 = acc[qm][0][m][n][j];
                        float g3 = acc[qm][1][m][n][j];
                        float hv = g1 / (1.f + __expf(-g1)) * g3;
                        h[hrow + ntile * 128 + wn * 32 + n * 16 + fr] = (__bf16)hv;
                    }
                }
            }
}

// phase 2: out += ce * (h @ w2^T). Block: 256 rows x 256 out-cols.
__global__ __launch_bounds__(512, 2) void phase2_bf16(
    const __bf16* __restrict__ h, const __bf16* __restrict__ w2b,
    const int* __restrict__ cnt, const int* __restrict__ prefix,
    const int* __restrict__ list, const float* __restrict__ coef,
    float* __restrict__ out)
{
    const int e = blockIdx.z;
    const int cnt_e = cnt[e];
    const int mtile = blockIdx.y;
    if (mtile * 256 >= cnt_e) return;
    const int ntile = blockIdx.x;
    const int base = prefix[e];
    const int rem = cnt_e - mtile * 256;

    extern __shared__ __bf16 smem[];
    __bf16* sA = smem;
    __bf16* sB = smem + 32768;

    const int tid = threadIdx.x;
    const int lane = tid & 63;
    const int wv = tid >> 6;
    const int wm = wv >> 2;
    const int wn = wv & 3;
    const int ri = lane >> 3;
    const int ch = lane & 7;
    const int scoff = (ch ^ ri) * 8;
    const int fr = lane & 15;
    const int fq = lane >> 4;

    const __bf16* aS[2][2];
#pragma unroll
    for (int qm = 0; qm < 2; ++qm)
#pragma unroll
        for (int j = 0; j < 2; ++j) {
            int row = qm * 128 + j * 64 + wv * 8 + ri;
            int rr = (row < rem) ? row : (rem - 1);
            aS[qm][j] = h + (size_t)(base + mtile * 256 + rr) * ID + scoff;
        }
    const __bf16* bS[2][2];
#pragma unroll
    for (int qh = 0; qh < 2; ++qh)
#pragma unroll
        for (int j = 0; j < 2; ++j) {
            int row = ntile * 256 + qh * 128 + j * 64 + wv * 8 + ri;
            bS[qh][j] = w2b + ((size_t)e * HD + row) * ID + scoff;
        }

    f32x4 acc[2][2][4][2];
#pragma unroll
    for (int a0 = 0; a0 < 2; ++a0)
#pragma unroll
        for (int a1 = 0; a1 < 2; ++a1)
#pragma unroll
            for (int m = 0; m < 4; ++m)
#pragma unroll
                for (int n = 0; n < 2; ++n)
                    acc[a0][a1][m][n] = (f32x4){0.f, 0.f, 0.f, 0.f};

    STAGE_A(0,0,0,0); STAGE_A(0,0,1,0);
    STAGE_B(0,0,0,0); STAGE_B(0,0,1,0);
    STAGE_B(0,1,0,0); STAGE_B(0,1,1,0);
    STAGE_A(0,1,0,0); STAGE_A(0,1,1,0);

    const int NTK = ID / 64;   // 22
    bf16x8 af[4][2], bf[2][2];
    for (int t = 0; t < NTK; ++t) {
        const int p = t & 1, q = p ^ 1;
        const int kn = ((t + 1 < NTK) ? (t + 1) : t) * 64;

        WAITV4; BARRIER;
        READ_A(p, 0); READ_B(p, 0);
        STAGE_A(q,0,0,kn); STAGE_A(q,0,1,kn);
        MFMA_PHASE(0, 0);

        WAITV4; BARRIER;
        READ_B(p, 1);
        STAGE_B(q,0,0,kn); STAGE_B(q,0,1,kn);
        MFMA_PHASE(0, 1);

        WAITV4; BARRIER;
        READ_A(p, 1); READ_B(p, 0);
        STAGE_B(q,1,0,kn); STAGE_B(q,1,1,kn);
        MFMA_PHASE(1, 0);

        BARRIER;
        READ_B(p, 1);
        STAGE_A(q,1,0,kn); STAGE_A(q,1,1,kn);
        MFMA_PHASE(1, 1);
    }

#pragma unroll
    for (int qm = 0; qm < 2; ++qm)
#pragma unroll
        for (int m = 0; m < 4; ++m)
#pragma unroll
            for (int j = 0; j < 4; ++j) {
                const int rl = qm * 128 + wm * 64 + m * 16 + fq * 4 + j;
                if (rl < rem) {
                    const int tt = list[e * NT + mtile * 256 + rl];
                    const float ce = coef[tt * NE + e];
                    float* orow = out + (size_t)tt * HD;
#pragma unroll
                    for (int qn = 0; qn < 2; ++qn)
#pragma unroll
                        for (int n = 0; n < 2; ++n) {
                            const int col = ntile * 256 + qn * 128 + wn * 32 + n * 16 + fr;
                            atomicAdd(&orow[col], ce * acc[qm][qn][m][n][j]);
                        }
                }
            }
}

// ============ fp32 fallback path (round-1, known-good) =====================
__global__ __launch_bounds__(256) void phase1_f32(
    const float* __restrict__ x, const float* __restrict__ w13,
    const int* __restrict__ cnt, const int* __restrict__ prefix,
    const int* __restrict__ list, __bf16* __restrict__ h)
{
    const int e = blockIdx.z;
    const int cnt_e = cnt[e];
    const int mtile = blockIdx.y;
    if (mtile * 128 >= cnt_e) return;
    const int ntile = blockIdx.x;
    const int base = prefix[e];
    const int rem = cnt_e - mtile * 128;

    __shared__ __align__(16) __bf16 sA[128][40];
    __shared__ __align__(16) __bf16 sB1[64][40];
    __shared__ __align__(16) __bf16 sB2[64][40];

    const int tid = threadIdx.x;
    const int lane = tid & 63;
    const int wv = tid >> 6;
    const int wr = wv >> 1;
    const int wc = wv & 1;

    const int ar = tid >> 1, ah = tid & 1;
    const int arc = (ar < rem) ? ar : (rem - 1);
    const int tok = list[e * NT + mtile * 128 + arc];
    const float* xa = x + (size_t)tok * HD + ah * 16;

    const int br = tid >> 2, bq = tid & 3;
    const float* w13e = w13 + (size_t)e * (2 * ID) * HD;
    const float* b1p = w13e + (size_t)(ntile * 64 + br) * HD + bq * 8;
    const float* b2p = w13e + (size_t)(ID + ntile * 64 + br) * HD + bq * 8;

    f32x4 acc1[4][2], acc2[4][2];
#pragma unroll
    for (int m = 0; m < 4; ++m)
#pragma unroll
        for (int n = 0; n < 2; ++n) {
            acc1[m][n] = (f32x4){0.f, 0.f, 0.f, 0.f};
            acc2[m][n] = (f32x4){0.f, 0.f, 0.f, 0.f};
        }

    const int kb = (lane >> 4) * 8;
    const int fr = lane & 15;
    const int fq = lane >> 4;

    for (int k0 = 0; k0 < HD; k0 += 32) {
        __syncthreads();
        {
            const float4* p = (const float4*)(xa + k0);
            float4 f0 = p[0], f1 = p[1], f2 = p[2], f3 = p[3];
            *(bf16x8*)&sA[ar][ah * 16] = cvt_bf8(f0, f1);
            *(bf16x8*)&sA[ar][ah * 16 + 8] = cvt_bf8(f2, f3);
        }
        {
            const float4* p = (const float4*)(b1p + k0);
            float4 f0 = p[0], f1 = p[1];
            *(bf16x8*)&sB1[br][bq * 8] = cvt_bf8(f0, f1);
        }
        {
            const float4* p = (const float4*)(b2p + k0);
            float4 f0 = p[0], f1 = p[1];
            *(bf16x8*)&sB2[br][bq * 8] = cvt_bf8(f0, f1);
        }
        __syncthreads();

        bf16x8 af[4], b1f[2], b2f[2];
#pragma unroll
        for (int m = 0; m < 4; ++m)
            af[m] = *(const bf16x8*)&sA[wr * 64 + m * 16 + fr][kb];
#pragma unroll
        for (int n = 0; n < 2; ++n) {
            b1f[n] = *(const bf16x8*)&sB1[wc * 32 + n * 16 + fr][kb];
            b2f[n] = *(const bf16x8*)&sB2[wc * 32 + n * 16 + fr][kb];
        }
#pragma unroll
        for (int m = 0; m < 4; ++m)
#pragma unroll
            for (int n = 0; n < 2; ++n) {
                acc1[m][n] = __builtin_amdgcn_mfma_f32_16x16x32_bf16(af[m], b1f[n], acc1[m][n], 0, 0, 0);
                acc2[m][n] = __builtin_amdgcn_mfma_f32_16x16x32_bf16(af[m], b2f[n], acc2[m][n], 0, 0, 0);
            }
    }

#pragma unroll
    for (int m = 0; m < 4; ++m) {
#pragma unroll
        for (int j = 0; j < 4; ++j) {
            const int rl = wr * 64 + m * 16 + fq * 4 + j;
            if (rl < rem) {
                const size_t hrow = (size_t)(base + mtile * 128 + rl) * ID;
#pragma unroll
                for (int n = 0; n < 2; ++n) {
                    float g1 = acc1[m][n][j];
                    float g2 = acc2[m][n][j];
                    float hv = g1 / (1.f + __expf(-g1)) * g2;
                    h[hrow + ntile * 64 + wc * 32 + n * 16 + fr] = (__bf16)hv;
                }
            }
        }
    }
}

__global__ __launch_bounds__(256) void phase2_f32(
    const __bf16* __restrict__ h, const float* __restrict__ w2,
    const int* __restrict__ cnt, const int* __restrict__ prefix,
    const int* __restrict__ list, const float* __restrict__ coef,
    float* __restrict__ out)
{
    const int e = blockIdx.z;
    const int cnt_e = cnt[e];
    const int mtile = blockIdx.y;
    if (mtile * 128 >= cnt_e) return;
    const int ntile = blockIdx.x;
    const int base = prefix[e];
    const int rem = cnt_e - mtile * 128;

    __shared__ __align__(16) __bf16 sA[128][40];
    __shared__ __align__(16) __bf16 sB[128][40];

    const int tid = threadIdx.x;
    const int lane = tid & 63;
    const int wv = tid >> 6;
    const int wr = wv >> 1;
    const int wc = wv & 1;

    const int ar = tid >> 1, ah = tid & 1;
    const int arc = (ar < rem) ? ar : (rem - 1);
    const __bf16* hap = h + (size_t)(base + mtile * 128 + arc) * ID + ah * 16;

    const float* w2e = w2 + (size_t)e * HD * ID;
    const float* bp = w2e + (size_t)(ntile * 128 + ar) * ID + ah * 16;

    f32x4 acc[4][4];
#pragma unroll
    for (int m = 0; m < 4; ++m)
#pragma unroll
        for (int n = 0; n < 4; ++n) acc[m][n] = (f32x4){0.f, 0.f, 0.f, 0.f};

    const int kb = (lane >> 4) * 8;
    const int fr = lane & 15;
    const int fq = lane >> 4;

    for (int k0 = 0; k0 < ID; k0 += 32) {
        __syncthreads();
        {
            const bf16x8* pa = (const bf16x8*)(hap + k0);
            *(bf16x8*)&sA[ar][ah * 16] = pa[0];
            *(bf16x8*)&sA[ar][ah * 16 + 8] = pa[1];
        }
        {
            const float4* p = (const float4*)(bp + k0);
            float4 f0 = p[0], f1 = p[1], f2 = p[2], f3 = p[3];
            *(bf16x8*)&sB[ar][ah * 16] = cvt_bf8(f0, f1);
            *(bf16x8*)&sB[ar][ah * 16 + 8] = cvt_bf8(f2, f3);
        }
        __syncthreads();

        bf16x8 af[4], bfr[4];
#pragma unroll
        for (int m = 0; m < 4; ++m)
            af[m] = *(const bf16x8*)&sA[wr * 64 + m * 16 + fr][kb];
#pragma unroll
        for (int n = 0; n < 4; ++n)
            bfr[n] = *(const bf16x8*)&sB[wc * 64 + n * 16 + fr][kb];
#pragma unroll
        for (int m = 0; m < 4; ++m)
#pragma unroll
            for (int n = 0; n < 4; ++n)
                acc[m][n] = __builtin_amdgcn_mfma_f32_16x16x32_bf16(af[m], bfr[n], acc[m][n], 0, 0, 0);
    }

#pragma unroll
    for (int m = 0; m < 4; ++m) {
#pragma unroll
        for (int j = 0; j < 4; ++j) {
            const int rl = wr * 64 + m * 16 + fq * 4 + j;
            if (rl < rem) {
                const int t = list[e * NT + mtile * 128 + rl];
                const float ce = coef[t * NE + e];
                float* orow = out + (size_t)t * HD;
#pragma unroll
                for (int n = 0; n < 4; ++n) {
                    const int col = ntile * 128 + wc * 64 + n * 16 + fr;
                    atomicAdd(&orow[col], ce * acc[m][n][j]);
                }
            }
        }
    }
}

extern "C" void kernel_launch(void* const* d_in, const int* in_sizes, int n_in,
                              void* d_out, int out_size, void* d_ws, size_t ws_size,
                              hipStream_t stream)
{
    const float* x   = (const float*)d_in[0];   // 8192 x 2048
    const float* gw  = (const float*)d_in[1];   // 8 x 2048
    const float* w13 = (const float*)d_in[2];   // 8 x 2816 x 2048
    const float* w2  = (const float*)d_in[3];   // 8 x 2048 x 1408
    float* out = (float*)d_out;                 // 16777216 out + 65536 logits

    char* ws = (char*)d_ws;
    int* cnt = (int*)ws;
    int* prefix = (int*)(ws + 32);
    int* list = (int*)(ws + 64);
    float* coef = (float*)(ws + 64 + NE * NT * 4);
    size_t off = ((size_t)64 + NE * NT * 4 + NT * NE * 4 + 255) & ~(size_t)255;

    const size_t nx = (size_t)NT * HD;            // 16.8M
    const size_t nw13 = (size_t)NE * 2 * ID * HD; // 46.1M
    const size_t nw2 = (size_t)NE * HD * ID;      // 23.1M
    const size_t nh = (size_t)2 * NT * ID;        // 23.1M elems (16384x1408)

    const size_t need = off + (nx + nw13 + nw2 + nh) * 2;

    hipMemsetAsync(cnt, 0, 32, stream);
    hipMemsetAsync(d_out, 0, (size_t)LOGIT_OFF * 4, stream);

    if (ws_size >= need) {
        __bf16* xb   = (__bf16*)(ws + off);
        __bf16* w13b = xb + nx;
        __bf16* w2b  = w13b + nw13;
        __bf16* h    = w2b + nw2;

        hipFuncSetAttribute(reinterpret_cast<const void*>(phase1_bf16),
                            hipFuncAttributeMaxDynamicSharedMemorySize, 131072);
        hipFuncSetAttribute(reinterpret_cast<const void*>(phase2_bf16),
                            hipFuncAttributeMaxDynamicSharedMemorySize, 131072);

        cvt_kernel<<<2048, 256, 0, stream>>>(w13, w13b, (int)(nw13 / 8));
        cvt_kernel<<<2048, 256, 0, stream>>>(w2, w2b, (int)(nw2 / 8));
        router_kernel<<<NT / 4, 256, 0, stream>>>(x, gw, out + LOGIT_OFF, cnt, list, coef, xb);
        prefix_kernel<<<1, 64, 0, stream>>>(cnt, prefix);
        phase1_bf16<<<dim3(ID / 128, NT / 256, NE), 512, 131072, stream>>>(xb, w13b, cnt, prefix, list, h);
        phase2_bf16<<<dim3(HD / 256, NT / 256, NE), 512, 131072, stream>>>(h, w2b, cnt, prefix, list, coef, out);
    } else {
        __bf16* h = (__bf16*)(ws + off);
        router_kernel<<<NT / 4, 256, 0, stream>>>(x, gw, out + LOGIT_OFF, cnt, list, coef, nullptr);
        prefix_kernel<<<1, 64, 0, stream>>>(cnt, prefix);
        phase1_f32<<<dim3(ID / 64, NT / 128, NE), 256, 0, stream>>>(x, w13, cnt, prefix, list, h);
        phase2_f32<<<dim3(HD / 128, NT / 128, NE), 256, 0, stream>>>(h, w2, cnt, prefix, list, coef, out);
    }
}

// Round 4
// 650.813 us; speedup vs baseline: 1.5733x; 1.1183x over previous
//
#include <hip/hip_runtime.h>
#include <stdint.h>

#define NT 8192      // tokens
#define HD 2048      // hidden
#define NE 8         // experts
#define ID 1408      // inter
#define LOGIT_OFF 16777216

typedef __bf16 bf16x8 __attribute__((ext_vector_type(8)));
typedef float f32x4 __attribute__((ext_vector_type(4)));

__device__ inline bf16x8 cvt_bf8(float4 a, float4 b) {
    bf16x8 v;
    v[0] = (__bf16)a.x; v[1] = (__bf16)a.y; v[2] = (__bf16)a.z; v[3] = (__bf16)a.w;
    v[4] = (__bf16)b.x; v[5] = (__bf16)b.y; v[6] = (__bf16)b.z; v[7] = (__bf16)b.w;
    return v;
}

__device__ inline void gload16(const void* g, void* l) {
    __builtin_amdgcn_global_load_lds(
        (const __attribute__((address_space(1))) unsigned int*)g,
        (__attribute__((address_space(3))) unsigned int*)l, 16, 0, 0);
}

#define WAITV4  asm volatile("s_waitcnt vmcnt(4)" ::: "memory")
#define BARRIER do { __builtin_amdgcn_s_barrier(); asm volatile("" ::: "memory"); } while (0)

// ---------------- fp32 -> bf16 convert (weights) ---------------------------
__global__ __launch_bounds__(256) void cvt_kernel(
    const float* __restrict__ src, __bf16* __restrict__ dst, int n8)
{
    for (int i = blockIdx.x * blockDim.x + threadIdx.x; i < n8;
         i += gridDim.x * blockDim.x) {
        const float4* p = (const float4*)(src + (size_t)i * 8);
        float4 a = p[0], b = p[1];
        *(bf16x8*)(dst + (size_t)i * 8) = cvt_bf8(a, b);
    }
}

// ---------------- router: logits fp32, top2, lists, slots; fused x->bf16 ---
__global__ __launch_bounds__(256) void router_kernel(
    const float* __restrict__ x, const float* __restrict__ gw,
    float* __restrict__ logits, int* __restrict__ cnt,
    int* __restrict__ list, float* __restrict__ coef,
    int4* __restrict__ tslot, float2* __restrict__ tww,
    __bf16* __restrict__ xb)
{
    const int wv = threadIdx.x >> 6, lane = threadIdx.x & 63;
    const int t = blockIdx.x * 4 + wv;
    const float* xt = x + (size_t)t * HD;
    float acc[NE];
#pragma unroll
    for (int e = 0; e < NE; ++e) acc[e] = 0.f;
    for (int k = lane; k < HD; k += 64) {
        float xv = xt[k];
#pragma unroll
        for (int e = 0; e < NE; ++e) acc[e] = fmaf(xv, gw[e * HD + k], acc[e]);
    }
#pragma unroll
    for (int off = 32; off > 0; off >>= 1) {
#pragma unroll
        for (int e = 0; e < NE; ++e) acc[e] += __shfl_down(acc[e], off);
    }
    if (lane == 0) {
#pragma unroll
        for (int e = 0; e < NE; ++e) logits[(size_t)t * NE + e] = acc[e];
        int b = 0;
#pragma unroll
        for (int e = 1; e < NE; ++e) if (acc[e] > acc[b]) b = e;
        int s = (b == 0) ? 1 : 0;
#pragma unroll
        for (int e = 0; e < NE; ++e) if (e != b && acc[e] > acc[s]) s = e;
        float er = __expf(acc[s] - acc[b]);
        float p1 = 1.f / (1.f + er);
        float p2 = er / (1.f + er);
#pragma unroll
        for (int e = 0; e < NE; ++e) coef[t * NE + e] = 0.f;
        coef[t * NE + b] = p1;
        coef[t * NE + s] = p2;
        int pos = atomicAdd(&cnt[b], 1); list[b * NT + pos] = t;
        int pos2 = atomicAdd(&cnt[s], 1); list[s * NT + pos2] = t;
        tslot[t] = make_int4(b, pos, s, pos2);
        tww[t] = make_float2(p1, p2);
    }
    if (xb) {
        for (int c = lane; c < HD / 8; c += 64) {
            const float4* p = (const float4*)(xt + c * 8);
            float4 a = p[0], b2 = p[1];
            *(bf16x8*)(xb + (size_t)t * HD + c * 8) = cvt_bf8(a, b2);
        }
    }
}

__global__ void prefix_kernel(const int* __restrict__ cnt, int* __restrict__ prefix)
{
    if (threadIdx.x == 0) {
        int s = 0;
        for (int e = 0; e < NE; ++e) { prefix[e] = s; s += cnt[e]; }
    }
}

// ---------------- combine: out[t] = w0*P[s0] + w1*P[s1] --------------------
__global__ __launch_bounds__(256) void combine_kernel(
    const __bf16* __restrict__ partial, const int* __restrict__ prefix,
    const int4* __restrict__ tslot, const float2* __restrict__ tww,
    float* __restrict__ out)
{
    const int t = blockIdx.x;
    int4 s = tslot[t];
    float2 w = tww[t];
    const __bf16* p0 = partial + (size_t)(prefix[s.x] + s.y) * HD;
    const __bf16* p1 = partial + (size_t)(prefix[s.z] + s.w) * HD;
    float* o = out + (size_t)t * HD;
    const int c = threadIdx.x;               // HD/8 == 256
    bf16x8 v0 = ((const bf16x8*)p0)[c];
    bf16x8 v1 = ((const bf16x8*)p1)[c];
    float4 r0, r1;
    r0.x = w.x * (float)v0[0] + w.y * (float)v1[0];
    r0.y = w.x * (float)v0[1] + w.y * (float)v1[1];
    r0.z = w.x * (float)v0[2] + w.y * (float)v1[2];
    r0.w = w.x * (float)v0[3] + w.y * (float)v1[3];
    r1.x = w.x * (float)v0[4] + w.y * (float)v1[4];
    r1.y = w.x * (float)v0[5] + w.y * (float)v1[5];
    r1.z = w.x * (float)v0[6] + w.y * (float)v1[6];
    r1.w = w.x * (float)v0[7] + w.y * (float)v1[7];
    ((float4*)(o + c * 8))[0] = r0;
    ((float4*)(o + c * 8))[1] = r1;
}

// ============ 256-tile phased bf16 kernels =================================
// BM=256, BK=64, 8 waves (2M x 4N). LDS 128 KiB: [parity][half][128][64] x A,B.
// Phase order (A0B0)(A0B1)(A1B1)(A1B0): B frags stay in regs, A regs reused.
// Stage order per tile: A0@ph1, B0@ph2, B1+A1@ph3. vmcnt(4) at ph1..ph3.

#define SA(P_,H_) (sA + (((P_)*2 + (H_)) * 128) * 64)
#define SB(P_,H_) (sB + (((P_)*2 + (H_)) * 128) * 64)

#define STAGE_A(P_,H_,J_,K_) gload16(aS[H_][J_] + (K_), SA(P_,H_) + ((J_)*64 + wv*8) * 64)
#define STAGE_B(P_,H_,J_,K_) gload16(bS[H_][J_] + (K_), SB(P_,H_) + ((J_)*64 + wv*8) * 64)

#define READ_AF(P_,H_) do { \
    _Pragma("unroll") for (int m_ = 0; m_ < 4; ++m_) { \
        const __bf16* rp_ = SA(P_,H_) + (wm*64 + m_*16 + fr) * 64; \
        aF[m_][0] = *(const bf16x8*)(rp_ + ((fq ^ (fr&7)) * 8)); \
        aF[m_][1] = *(const bf16x8*)(rp_ + (((4+fq) ^ (fr&7)) * 8)); \
    } } while (0)

#define READ_BF(D_,P_,H_) do { \
    _Pragma("unroll") for (int n_ = 0; n_ < 2; ++n_) { \
        const __bf16* rp_ = SB(P_,H_) + (wn*32 + n_*16 + fr) * 64; \
        D_[n_][0] = *(const bf16x8*)(rp_ + ((fq ^ (fr&7)) * 8)); \
        D_[n_][1] = *(const bf16x8*)(rp_ + (((4+fq) ^ (fr&7)) * 8)); \
    } } while (0)

#define MFMA16(QM_,QH_,BF_) do { \
    __builtin_amdgcn_s_setprio(1); \
    _Pragma("unroll") for (int m_ = 0; m_ < 4; ++m_) \
    _Pragma("unroll") for (int n_ = 0; n_ < 2; ++n_) { \
        acc[QM_][QH_][m_][n_] = __builtin_amdgcn_mfma_f32_16x16x32_bf16(aF[m_][0], BF_[n_][0], acc[QM_][QH_][m_][n_], 0, 0, 0); \
        acc[QM_][QH_][m_][n_] = __builtin_amdgcn_mfma_f32_16x16x32_bf16(aF[m_][1], BF_[n_][1], acc[QM_][QH_][m_][n_], 0, 0, 0); \
    } \
    __builtin_amdgcn_s_setprio(0); \
} while (0)

#define KLOOP_PHASES(Q00_,Q01_,Q11_,Q10_) \
    for (int t = 0; t < NTK; ++t) { \
        const int p = t & 1, q = p ^ 1; \
        const int kn = ((t + 1 < NTK) ? (t + 1) : t) * 64; \
        WAITV4; BARRIER; \
        READ_AF(p, 0); READ_BF(bQ0, p, 0); \
        STAGE_A(q,0,0,kn); STAGE_A(q,0,1,kn); \
        MFMA16 Q00_; \
        WAITV4; BARRIER; \
        READ_BF(bQ1, p, 1); \
        STAGE_B(q,0,0,kn); STAGE_B(q,0,1,kn); \
        MFMA16 Q01_; \
        WAITV4; BARRIER; \
        READ_AF(p, 1); \
        STAGE_B(q,1,0,kn); STAGE_B(q,1,1,kn); \
        MFMA16 Q11_; \
        STAGE_A(q,1,0,kn); STAGE_A(q,1,1,kn); \
        MFMA16 Q10_; \
    }

#define PROLOGUE_STAGE \
    STAGE_A(0,0,0,0); STAGE_A(0,0,1,0); \
    STAGE_B(0,0,0,0); STAGE_B(0,0,1,0); \
    STAGE_B(0,1,0,0); STAGE_B(0,1,1,0); \
    STAGE_A(0,1,0,0); STAGE_A(0,1,1,0)

// phase 1: h = silu(x@w1^T) * (x@w3^T). Block: 256 rows x 128 h-cols.
__global__ __launch_bounds__(512, 2) void phase1_bf16(
    const __bf16* __restrict__ xb, const __bf16* __restrict__ w13b,
    const int* __restrict__ cnt, const int* __restrict__ prefix,
    const int* __restrict__ list, __bf16* __restrict__ h)
{
    const int e = blockIdx.z;
    const int cnt_e = cnt[e];
    const int mtile = blockIdx.y;
    if (mtile * 256 >= cnt_e) return;
    const int ntile = blockIdx.x;
    const int base = prefix[e];
    const int rem = cnt_e - mtile * 256;

    extern __shared__ __bf16 smem[];
    __bf16* sA = smem;
    __bf16* sB = smem + 32768;

    const int tid = threadIdx.x;
    const int lane = tid & 63;
    const int wv = tid >> 6;
    const int wm = wv >> 2;
    const int wn = wv & 3;
    const int ri = lane >> 3;
    const int ch = lane & 7;
    const int scoff = (ch ^ ri) * 8;
    const int fr = lane & 15;
    const int fq = lane >> 4;

    const __bf16* aS[2][2];
#pragma unroll
    for (int qm = 0; qm < 2; ++qm)
#pragma unroll
        for (int j = 0; j < 2; ++j) {
            int row = qm * 128 + j * 64 + wv * 8 + ri;
            int rr = (row < rem) ? row : (rem - 1);
            int tok = list[e * NT + mtile * 256 + rr];
            aS[qm][j] = xb + (size_t)tok * HD + scoff;
        }
    const __bf16* bS[2][2];
    const size_t w13e = (size_t)e * (2 * ID);
#pragma unroll
    for (int j = 0; j < 2; ++j) {
        int row = ntile * 128 + j * 64 + wv * 8 + ri;
        bS[0][j] = w13b + (w13e + row) * HD + scoff;
        bS[1][j] = w13b + (w13e + ID + row) * HD + scoff;
    }

    f32x4 acc[2][2][4][2];
#pragma unroll
    for (int a0 = 0; a0 < 2; ++a0)
#pragma unroll
        for (int a1 = 0; a1 < 2; ++a1)
#pragma unroll
            for (int m = 0; m < 4; ++m)
#pragma unroll
                for (int n = 0; n < 2; ++n)
                    acc[a0][a1][m][n] = (f32x4){0.f, 0.f, 0.f, 0.f};

    PROLOGUE_STAGE;

    const int NTK = HD / 64;   // 32
    bf16x8 aF[4][2], bQ0[2][2], bQ1[2][2];
    KLOOP_PHASES((0,0,bQ0), (0,1,bQ1), (1,1,bQ1), (1,0,bQ0))

    // epilogue: h = silu(g1) * g3
#pragma unroll
    for (int qm = 0; qm < 2; ++qm)
#pragma unroll
        for (int m = 0; m < 4; ++m)
#pragma unroll
            for (int j = 0; j < 4; ++j) {
                const int rl = qm * 128 + wm * 64 + m * 16 + fq * 4 + j;
                if (rl < rem) {
                    const size_t hrow = (size_t)(base + mtile * 256 + rl) * ID;
#pragma unroll
                    for (int n = 0; n < 2; ++n) {
                        float g1 = acc[qm][0][m][n][j];
                        float g3 = acc[qm][1][m][n][j];
                        float hv = g1 / (1.f + __expf(-g1)) * g3;
                        h[hrow + ntile * 128 + wn * 32 + n * 16 + fr] = (__bf16)hv;
                    }
                }
            }
}

// phase 2: P[slot] = h @ w2^T (partial path) or out += ce*(h@w2^T) (atomic).
__global__ __launch_bounds__(512, 2) void phase2_bf16(
    const __bf16* __restrict__ h, const __bf16* __restrict__ w2b,
    const int* __restrict__ cnt, const int* __restrict__ prefix,
    const int* __restrict__ list, const float* __restrict__ coef,
    float* __restrict__ out, __bf16* __restrict__ partial)
{
    const int e = blockIdx.z;
    const int cnt_e = cnt[e];
    const int mtile = blockIdx.y;
    if (mtile * 256 >= cnt_e) return;
    const int ntile = blockIdx.x;
    const int base = prefix[e];
    const int rem = cnt_e - mtile * 256;

    extern __shared__ __bf16 smem[];
    __bf16* sA = smem;
    __bf16* sB = smem + 32768;

    const int tid = threadIdx.x;
    const int lane = tid & 63;
    const int wv = tid >> 6;
    const int wm = wv >> 2;
    const int wn = wv & 3;
    const int ri = lane >> 3;
    const int ch = lane & 7;
    const int scoff = (ch ^ ri) * 8;
    const int fr = lane & 15;
    const int fq = lane >> 4;

    const __bf16* aS[2][2];
#pragma unroll
    for (int qm = 0; qm < 2; ++qm)
#pragma unroll
        for (int j = 0; j < 2; ++j) {
            int row = qm * 128 + j * 64 + wv * 8 + ri;
            int rr = (row < rem) ? row : (rem - 1);
            aS[qm][j] = h + (size_t)(base + mtile * 256 + rr) * ID + scoff;
        }
    const __bf16* bS[2][2];
#pragma unroll
    for (int qh = 0; qh < 2; ++qh)
#pragma unroll
        for (int j = 0; j < 2; ++j) {
            int row = ntile * 256 + qh * 128 + j * 64 + wv * 8 + ri;
            bS[qh][j] = w2b + ((size_t)e * HD + row) * ID + scoff;
        }

    f32x4 acc[2][2][4][2];
#pragma unroll
    for (int a0 = 0; a0 < 2; ++a0)
#pragma unroll
        for (int a1 = 0; a1 < 2; ++a1)
#pragma unroll
            for (int m = 0; m < 4; ++m)
#pragma unroll
                for (int n = 0; n < 2; ++n)
                    acc[a0][a1][m][n] = (f32x4){0.f, 0.f, 0.f, 0.f};

    PROLOGUE_STAGE;

    const int NTK = ID / 64;   // 22
    bf16x8 aF[4][2], bQ0[2][2], bQ1[2][2];
    KLOOP_PHASES((0,0,bQ0), (0,1,bQ1), (1,1,bQ1), (1,0,bQ0))

    if (partial) {
#pragma unroll
        for (int qm = 0; qm < 2; ++qm)
#pragma unroll
            for (int m = 0; m < 4; ++m)
#pragma unroll
                for (int j = 0; j < 4; ++j) {
                    const int rl = qm * 128 + wm * 64 + m * 16 + fq * 4 + j;
                    if (rl < rem) {
                        __bf16* prow = partial + (size_t)(base + mtile * 256 + rl) * HD;
#pragma unroll
                        for (int qn = 0; qn < 2; ++qn)
#pragma unroll
                            for (int n = 0; n < 2; ++n) {
                                const int col = ntile * 256 + qn * 128 + wn * 32 + n * 16 + fr;
                                prow[col] = (__bf16)acc[qm][qn][m][n][j];
                            }
                    }
                }
    } else {
#pragma unroll
        for (int qm = 0; qm < 2; ++qm)
#pragma unroll
            for (int m = 0; m < 4; ++m)
#pragma unroll
                for (int j = 0; j < 4; ++j) {
                    const int rl = qm * 128 + wm * 64 + m * 16 + fq * 4 + j;
                    if (rl < rem) {
                        const int tt = list[e * NT + mtile * 256 + rl];
                        const float ce = coef[tt * NE + e];
                        float* orow = out + (size_t)tt * HD;
#pragma unroll
                        for (int qn = 0; qn < 2; ++qn)
#pragma unroll
                            for (int n = 0; n < 2; ++n) {
                                const int col = ntile * 256 + qn * 128 + wn * 32 + n * 16 + fr;
                                atomicAdd(&orow[col], ce * acc[qm][qn][m][n][j]);
                            }
                    }
                }
    }
}

// ============ fp32 fallback path (round-1, known-good) =====================
__global__ __launch_bounds__(256) void phase1_f32(
    const float* __restrict__ x, const float* __restrict__ w13,
    const int* __restrict__ cnt, const int* __restrict__ prefix,
    const int* __restrict__ list, __bf16* __restrict__ h)
{
    const int e = blockIdx.z;
    const int cnt_e = cnt[e];
    const int mtile = blockIdx.y;
    if (mtile * 128 >= cnt_e) return;
    const int ntile = blockIdx.x;
    const int base = prefix[e];
    const int rem = cnt_e - mtile * 128;

    __shared__ __align__(16) __bf16 sA[128][40];
    __shared__ __align__(16) __bf16 sB1[64][40];
    __shared__ __align__(16) __bf16 sB2[64][40];

    const int tid = threadIdx.x;
    const int lane = tid & 63;
    const int wv = tid >> 6;
    const int wr = wv >> 1;
    const int wc = wv & 1;

    const int ar = tid >> 1, ah = tid & 1;
    const int arc = (ar < rem) ? ar : (rem - 1);
    const int tok = list[e * NT + mtile * 128 + arc];
    const float* xa = x + (size_t)tok * HD + ah * 16;

    const int br = tid >> 2, bq = tid & 3;
    const float* w13e = w13 + (size_t)e * (2 * ID) * HD;
    const float* b1p = w13e + (size_t)(ntile * 64 + br) * HD + bq * 8;
    const float* b2p = w13e + (size_t)(ID + ntile * 64 + br) * HD + bq * 8;

    f32x4 acc1[4][2], acc2[4][2];
#pragma unroll
    for (int m = 0; m < 4; ++m)
#pragma unroll
        for (int n = 0; n < 2; ++n) {
            acc1[m][n] = (f32x4){0.f, 0.f, 0.f, 0.f};
            acc2[m][n] = (f32x4){0.f, 0.f, 0.f, 0.f};
        }

    const int kb = (lane >> 4) * 8;
    const int fr = lane & 15;
    const int fq = lane >> 4;

    for (int k0 = 0; k0 < HD; k0 += 32) {
        __syncthreads();
        {
            const float4* p = (const float4*)(xa + k0);
            float4 f0 = p[0], f1 = p[1], f2 = p[2], f3 = p[3];
            *(bf16x8*)&sA[ar][ah * 16] = cvt_bf8(f0, f1);
            *(bf16x8*)&sA[ar][ah * 16 + 8] = cvt_bf8(f2, f3);
        }
        {
            const float4* p = (const float4*)(b1p + k0);
            float4 f0 = p[0], f1 = p[1];
            *(bf16x8*)&sB1[br][bq * 8] = cvt_bf8(f0, f1);
        }
        {
            const float4* p = (const float4*)(b2p + k0);
            float4 f0 = p[0], f1 = p[1];
            *(bf16x8*)&sB2[br][bq * 8] = cvt_bf8(f0, f1);
        }
        __syncthreads();

        bf16x8 af[4], b1f[2], b2f[2];
#pragma unroll
        for (int m = 0; m < 4; ++m)
            af[m] = *(const bf16x8*)&sA[wr * 64 + m * 16 + fr][kb];
#pragma unroll
        for (int n = 0; n < 2; ++n) {
            b1f[n] = *(const bf16x8*)&sB1[wc * 32 + n * 16 + fr][kb];
            b2f[n] = *(const bf16x8*)&sB2[wc * 32 + n * 16 + fr][kb];
        }
#pragma unroll
        for (int m = 0; m < 4; ++m)
#pragma unroll
            for (int n = 0; n < 2; ++n) {
                acc1[m][n] = __builtin_amdgcn_mfma_f32_16x16x32_bf16(af[m], b1f[n], acc1[m][n], 0, 0, 0);
                acc2[m][n] = __builtin_amdgcn_mfma_f32_16x16x32_bf16(af[m], b2f[n], acc2[m][n], 0, 0, 0);
            }
    }

#pragma unroll
    for (int m = 0; m < 4; ++m) {
#pragma unroll
        for (int j = 0; j < 4; ++j) {
            const int rl = wr * 64 + m * 16 + fq * 4 + j;
            if (rl < rem) {
                const size_t hrow = (size_t)(base + mtile * 128 + rl) * ID;
#pragma unroll
                for (int n = 0; n < 2; ++n) {
                    float g1 = acc1[m][n][j];
                    float g2 = acc2[m][n][j];
                    float hv = g1 / (1.f + __expf(-g1)) * g2;
                    h[hrow + ntile * 64 + wc * 32 + n * 16 + fr] = (__bf16)hv;
                }
            }
        }
    }
}

__global__ __launch_bounds__(256) void phase2_f32(
    const __bf16* __restrict__ h, const float* __restrict__ w2,
    const int* __restrict__ cnt, const int* __restrict__ prefix,
    const int* __restrict__ list, const float* __restrict__ coef,
    float* __restrict__ out)
{
    const int e = blockIdx.z;
    const int cnt_e = cnt[e];
    const int mtile = blockIdx.y;
    if (mtile * 128 >= cnt_e) return;
    const int ntile = blockIdx.x;
    const int base = prefix[e];
    const int rem = cnt_e - mtile * 128;

    __shared__ __align__(16) __bf16 sA[128][40];
    __shared__ __align__(16) __bf16 sB[128][40];

    const int tid = threadIdx.x;
    const int lane = tid & 63;
    const int wv = tid >> 6;
    const int wr = wv >> 1;
    const int wc = wv & 1;

    const int ar = tid >> 1, ah = tid & 1;
    const int arc = (ar < rem) ? ar : (rem - 1);
    const __bf16* hap = h + (size_t)(base + mtile * 128 + arc) * ID + ah * 16;

    const float* w2e = w2 + (size_t)e * HD * ID;
    const float* bp = w2e + (size_t)(ntile * 128 + ar) * ID + ah * 16;

    f32x4 acc[4][4];
#pragma unroll
    for (int m = 0; m < 4; ++m)
#pragma unroll
        for (int n = 0; n < 4; ++n) acc[m][n] = (f32x4){0.f, 0.f, 0.f, 0.f};

    const int kb = (lane >> 4) * 8;
    const int fr = lane & 15;
    const int fq = lane >> 4;

    for (int k0 = 0; k0 < ID; k0 += 32) {
        __syncthreads();
        {
            const bf16x8* pa = (const bf16x8*)(hap + k0);
            *(bf16x8*)&sA[ar][ah * 16] = pa[0];
            *(bf16x8*)&sA[ar][ah * 16 + 8] = pa[1];
        }
        {
            const float4* p = (const float4*)(bp + k0);
            float4 f0 = p[0], f1 = p[1], f2 = p[2], f3 = p[3];
            *(bf16x8*)&sB[ar][ah * 16] = cvt_bf8(f0, f1);
            *(bf16x8*)&sB[ar][ah * 16 + 8] = cvt_bf8(f2, f3);
        }
        __syncthreads();

        bf16x8 af[4], bfr[4];
#pragma unroll
        for (int m = 0; m < 4; ++m)
            af[m] = *(const bf16x8*)&sA[wr * 64 + m * 16 + fr][kb];
#pragma unroll
        for (int n = 0; n < 4; ++n)
            bfr[n] = *(const bf16x8*)&sB[wc * 64 + n * 16 + fr][kb];
#pragma unroll
        for (int m = 0; m < 4; ++m)
#pragma unroll
            for (int n = 0; n < 4; ++n)
                acc[m][n] = __builtin_amdgcn_mfma_f32_16x16x32_bf16(af[m], bfr[n], acc[m][n], 0, 0, 0);
    }

#pragma unroll
    for (int m = 0; m < 4; ++m) {
#pragma unroll
        for (int j = 0; j < 4; ++j) {
            const int rl = wr * 64 + m * 16 + fq * 4 + j;
            if (rl < rem) {
                const int t = list[e * NT + mtile * 128 + rl];
                const float ce = coef[t * NE + e];
                float* orow = out + (size_t)t * HD;
#pragma unroll
                for (int n = 0; n < 4; ++n) {
                    const int col = ntile * 128 + wc * 64 + n * 16 + fr;
                    atomicAdd(&orow[col], ce * acc[m][n][j]);
                }
            }
        }
    }
}

extern "C" void kernel_launch(void* const* d_in, const int* in_sizes, int n_in,
                              void* d_out, int out_size, void* d_ws, size_t ws_size,
                              hipStream_t stream)
{
    const float* x   = (const float*)d_in[0];   // 8192 x 2048
    const float* gw  = (const float*)d_in[1];   // 8 x 2048
    const float* w13 = (const float*)d_in[2];   // 8 x 2816 x 2048
    const float* w2  = (const float*)d_in[3];   // 8 x 2048 x 1408
    float* out = (float*)d_out;                 // 16777216 out + 65536 logits

    char* ws = (char*)d_ws;
    int* cnt = (int*)ws;                                     // 32 B
    int* prefix = (int*)(ws + 32);                           // 32 B
    int* list = (int*)(ws + 64);                             // 256 KB
    float* coef = (float*)(ws + 64 + NE * NT * 4);           // 256 KB
    int4* tslot = (int4*)(ws + 64 + NE * NT * 4 + NT * NE * 4);     // 128 KB
    float2* tww = (float2*)((char*)tslot + NT * 16);         // 64 KB
    size_t off = ((size_t)64 + NE*NT*4 + NT*NE*4 + NT*16 + NT*8 + 1023) & ~(size_t)1023;

    const size_t nx = (size_t)NT * HD;            // 16.8M
    const size_t nw13 = (size_t)NE * 2 * ID * HD; // 46.1M
    const size_t nw2 = (size_t)NE * HD * ID;      // 23.1M
    const size_t nh = (size_t)2 * NT * ID;        // 23.1M
    const size_t np = (size_t)2 * NT * HD;        // 33.6M

    const size_t need_mid  = off + (nx + nw13 + nw2 + nh) * 2;
    const size_t need_full = need_mid + np * 2;

    hipMemsetAsync(cnt, 0, 32, stream);

    if (ws_size >= need_mid) {
        __bf16* xb   = (__bf16*)(ws + off);
        __bf16* w13b = xb + nx;
        __bf16* w2b  = w13b + nw13;
        __bf16* h    = w2b + nw2;
        __bf16* partial = (ws_size >= need_full) ? (h + nh) : nullptr;

        hipFuncSetAttribute(reinterpret_cast<const void*>(phase1_bf16),
                            hipFuncAttributeMaxDynamicSharedMemorySize, 131072);
        hipFuncSetAttribute(reinterpret_cast<const void*>(phase2_bf16),
                            hipFuncAttributeMaxDynamicSharedMemorySize, 131072);

        if (!partial) hipMemsetAsync(out, 0, (size_t)LOGIT_OFF * 4, stream);

        cvt_kernel<<<2048, 256, 0, stream>>>(w13, w13b, (int)(nw13 / 8));
        cvt_kernel<<<2048, 256, 0, stream>>>(w2, w2b, (int)(nw2 / 8));
        router_kernel<<<NT / 4, 256, 0, stream>>>(x, gw, out + LOGIT_OFF, cnt, list, coef, tslot, tww, xb);
        prefix_kernel<<<1, 64, 0, stream>>>(cnt, prefix);
        phase1_bf16<<<dim3(ID / 128, NT / 256, NE), 512, 131072, stream>>>(xb, w13b, cnt, prefix, list, h);
        phase2_bf16<<<dim3(HD / 256, NT / 256, NE), 512, 131072, stream>>>(h, w2b, cnt, prefix, list, coef, out, partial);
        if (partial)
            combine_kernel<<<NT, 256, 0, stream>>>(partial, prefix, tslot, tww, out);
    } else {
        __bf16* h = (__bf16*)(ws + off);
        hipMemsetAsync(out, 0, (size_t)LOGIT_OFF * 4, stream);
        router_kernel<<<NT / 4, 256, 0, stream>>>(x, gw, out + LOGIT_OFF, cnt, list, coef, tslot, tww, nullptr);
        prefix_kernel<<<1, 64, 0, stream>>>(cnt, prefix);
        phase1_f32<<<dim3(ID / 64, NT / 128, NE), 256, 0, stream>>>(x, w13, cnt, prefix, list, h);
        phase2_f32<<<dim3(HD / 128, NT / 128, NE), 256, 0, stream>>>(h, w2, cnt, prefix, list, coef, out);
    }
}